// Round 10
// baseline (101.501 us; speedup 1.0000x reference)
//
#include <hip/hip_runtime.h>
#include <hip/hip_bf16.h>
#include <math.h>

#define N_ROWS 8192
#define D_DIM  256
#define BM 128                        // rows per block (= per wave-tile)
#define BN 64                         // cols per j-step (4 waves x 16-col strips)
#define JSPLIT 8
#define JRANGE (N_ROWS / JSPLIT)      // 1024
#define NT (JRANGE / BN)              // 16 j-steps per block

typedef __attribute__((ext_vector_type(4))) float f32x4;

// total logit scale: exp(dot*2) == exp2(dot * 2*log2(e)); split sqrt onto A and B
#define CAST_SCALE 1.6986388f         // sqrt(2 * log2(e)) = sqrt(2.88539)

__device__ __forceinline__ float fast_exp2(float x) {
#if __has_builtin(__builtin_amdgcn_exp2f)
    return __builtin_amdgcn_exp2f(x);
#else
    return exp2f(x);
#endif
}

// ------- kernel 1: L2-normalize rows, scale, cast to fp8 e4m3 (+ zero accum) -
__global__ void norm_cast_kernel(const float* __restrict__ out0,
                                 const float* __restrict__ out1,
                                 unsigned char* __restrict__ a_f8,
                                 unsigned char* __restrict__ b_f8,
                                 float* __restrict__ zero_me) {   // pos+all, 2*N floats
    int gtid = blockIdx.x * blockDim.x + threadIdx.x;
    if (gtid < 2 * N_ROWS) zero_me[gtid] = 0.0f;

    int wave = gtid >> 6;
    int lane = threadIdx.x & 63;
    const float* src    = (wave < N_ROWS) ? out0 : out1;
    unsigned char* dst  = (wave < N_ROWS) ? a_f8 : b_f8;
    int row = (wave < N_ROWS) ? wave : wave - N_ROWS;

    float4 v = *reinterpret_cast<const float4*>(src + (size_t)row * D_DIM + lane * 4);
    float ss = v.x * v.x + v.y * v.y + v.z * v.z + v.w * v.w;
    #pragma unroll
    for (int off = 32; off; off >>= 1) ss += __shfl_xor(ss, off);
    float inv = CAST_SCALE / fmaxf(sqrtf(ss), 1e-12f);

    int packed = __builtin_amdgcn_cvt_pk_fp8_f32(v.x * inv, v.y * inv, 0, 0);
    packed     = __builtin_amdgcn_cvt_pk_fp8_f32(v.z * inv, v.w * inv, packed, 1);
    *reinterpret_cast<unsigned int*>(dst + (size_t)row * D_DIM + lane * 4) =
        (unsigned int)packed;
}

// ------- kernel 2: fp8 flash-style fused GEMM + exp2 + masked row-sums ------
// 512 blocks = 64 row-tiles x 8 j-splits (jsplit = blockIdx&7 -> per-XCD).
// 4 waves, EACH with a 128x16 wave-tile (m_rep=8, n_rep=1): A-slice 128 rows x
// 256 k fp8 = 128 VGPR, PINNED. B-read LDS traffic = 1/4 of the bf16/64-row
// design. B double-buffered in LDS (2x16 KB), global_load_lds(16B) staging,
// 16B-slot XOR swizzle: LDS[row][s] = global[row][s ^ (row&15)].
__global__ __launch_bounds__(256, 2)
void fused_flash_kernel(const unsigned char* __restrict__ A,
                        const unsigned char* __restrict__ B,
                        const int* __restrict__ labels,
                        float* __restrict__ pos_sum,
                        float* __restrict__ all_sum) {
    __shared__ unsigned char Bs[2][BN * D_DIM];   // 2 x 16 KB

    const int tid    = threadIdx.x;
    const int lane   = tid & 63;
    const int wid    = tid >> 6;        // 0..3 -> 16-col strip
    const int lane16 = lane & 15;
    const int kgrp   = lane >> 4;       // 0..3

    const int jsplit = blockIdx.x & 7;
    const int rowt   = blockIdx.x >> 3;
    const int i0     = rowt * BM;
    const int jbase  = jsplit * JRANGE;

    // ---- A fragments -> registers (once), PINNED (128 VGPR) ----
    // frag (m, ks): row = i0 + m*16 + lane16, bytes [ks*32 + kgrp*8, +8)
    long af[8][8];
    #pragma unroll
    for (int m = 0; m < 8; ++m) {
        const unsigned char* ap =
            A + (size_t)(i0 + m * 16 + lane16) * D_DIM + kgrp * 8;
        #pragma unroll
        for (int ks = 0; ks < 8; ++ks)
            af[m][ks] = *reinterpret_cast<const long*>(ap + ks * 32);
    }
    #pragma unroll
    for (int m = 0; m < 8; ++m)
        #pragma unroll
        for (int ks = 0; ks < 8; ++ks)
            asm volatile("" : "+v"(af[m][ks]));

    // row labels (0..99 fit in a byte), packed 4-per-int, pinned (8 VGPR)
    int labp[8];
    #pragma unroll
    for (int m = 0; m < 8; ++m) {
        int4 v = *reinterpret_cast<const int4*>(labels + i0 + m * 16 + kgrp * 4);
        labp[m] = v.x | (v.y << 8) | (v.z << 16) | (v.w << 24);
        asm volatile("" : "+v"(labp[m]));
    }

    // ---- B staging: 16 chunks of 1KB (4 rows x 256B), 4 per wave ----
    auto stage = [&](int buf, int t) {
        const int jrow0 = jbase + t * BN;
        #pragma unroll
        for (int cc = 0; cc < 4; ++cc) {
            int c  = wid * 4 + cc;                  // chunk 0..15 (wave-uniform)
            int gr = jrow0 + c * 4 + kgrp;          // global B row
            const unsigned char* src =
                B + (size_t)gr * D_DIM + ((lane16 ^ (gr & 15)) << 4);
            __builtin_amdgcn_global_load_lds(
                (const __attribute__((address_space(1))) void*)src,
                (__attribute__((address_space(3))) void*)(&Bs[buf][0] + c * 1024),
                16, 0, 0);
        }
    };

    float allp[8][4] = {};
    float posp[8][4] = {};

    stage(0, 0);
    __syncthreads();

    for (int t = 0; t < NT; ++t) {
        const int cur = t & 1;
        if (t + 1 < NT) stage(cur ^ 1, t + 1);

        // column label (one per lane; issue early, hides under MFMA)
        const int labc = labels[jbase + t * BN + wid * 16 + lane16];

        // ---- compute 128x16 logits strip: 64 MFMA per wave ----
        f32x4 acc[8] = {};
        const int tr = wid * 16 + lane16;           // B row (output col) in tile
        __builtin_amdgcn_s_setprio(1);
        #pragma unroll
        for (int ks = 0; ks < 8; ++ks) {
            // logical 16B slot = 2*ks + (kgrp>>1); half (8B) = kgrp&1
            int byteoff = tr * 256
                        + ((((ks << 1) + (kgrp >> 1)) ^ lane16) << 4)
                        + ((kgrp & 1) << 3);
            long bv = *reinterpret_cast<const long*>(&Bs[cur][0] + byteoff);
            #pragma unroll
            for (int m = 0; m < 8; ++m)
                acc[m] = __builtin_amdgcn_mfma_f32_16x16x32_fp8_fp8(
                    af[m][ks], bv, acc[m], 0, 0, 0);
        }
        __builtin_amdgcn_s_setprio(0);

        __syncthreads();   // all reads of Bs[cur] done; stage(t+1) drained

        // ---- epilogue: exp2 + mask, accumulate row sums in registers ----
        #pragma unroll
        for (int m = 0; m < 8; ++m) {
            #pragma unroll
            for (int r = 0; r < 4; ++r) {
                float e = fast_exp2(acc[m][r]);     // == exp(logit/T)
                allp[m][r] += e;
                int lr = (labp[m] >> (r * 8)) & 0xFF;
                posp[m][r] += (lr == labc) ? e : 0.0f;
            }
        }
    }

    // ---- final: reduce across the 16 col-lanes, one atomic per row ----
    #pragma unroll
    for (int m = 0; m < 8; ++m) {
        #pragma unroll
        for (int r = 0; r < 4; ++r) {
            float a = allp[m][r], p = posp[m][r];
            #pragma unroll
            for (int off = 1; off < 16; off <<= 1) {
                a += __shfl_xor(a, off);
                p += __shfl_xor(p, off);
            }
            if (lane16 == 0) {
                int grow = i0 + m * 16 + kgrp * 4 + r;
                atomicAdd(&all_sum[grow], a);
                atomicAdd(&pos_sum[grow], p);
            }
        }
    }
}

// ---------------- kernel 3: final loss reduction ----------------------------
__global__ void loss_kernel(const float* __restrict__ pos_sum,
                            const float* __restrict__ all_sum,
                            float* __restrict__ out) {
    float acc = 0.0f;
    for (int i = threadIdx.x; i < N_ROWS; i += 1024)
        acc += logf(pos_sum[i] / all_sum[i]);
    #pragma unroll
    for (int off = 32; off; off >>= 1) acc += __shfl_xor(acc, off);
    __shared__ float red[16];
    int wv = threadIdx.x >> 6, lane = threadIdx.x & 63;
    if (lane == 0) red[wv] = acc;
    __syncthreads();
    if (threadIdx.x < 64) {
        float s = (threadIdx.x < 16) ? red[threadIdx.x] : 0.0f;
        #pragma unroll
        for (int off = 8; off; off >>= 1) s += __shfl_xor(s, off);
        if (threadIdx.x == 0) out[0] = -s / (float)N_ROWS;
    }
}

// ---------------- launch -----------------------------------------------------
extern "C" void kernel_launch(void* const* d_in, const int* in_sizes, int n_in,
                              void* d_out, int out_size, void* d_ws, size_t ws_size,
                              hipStream_t stream) {
    const float* out0   = (const float*)d_in[0];
    const float* out1   = (const float*)d_in[1];
    const int*   labels = (const int*)d_in[2];
    float*       out    = (float*)d_out;

    unsigned char* a_f8 = (unsigned char*)d_ws;
    unsigned char* b_f8 = a_f8 + (size_t)N_ROWS * D_DIM;
    float* pos  = (float*)(b_f8 + (size_t)N_ROWS * D_DIM);
    float* alls = pos + N_ROWS;

    norm_cast_kernel<<<2 * N_ROWS / 4, 256, 0, stream>>>(out0, out1, a_f8, b_f8, pos);

    fused_flash_kernel<<<JSPLIT * (N_ROWS / BM), 256, 0, stream>>>(a_f8, b_f8, labels, pos, alls);

    loss_kernel<<<1, 1024, 0, stream>>>(pos, alls, out);
}

// Round 11
// 54.014 us; speedup vs baseline: 1.8792x; 1.8792x over previous
//
#include <hip/hip_runtime.h>
#include <hip/hip_bf16.h>
#include <math.h>

#define N_ROWS 8192
#define D_DIM  256
#define BM 128
#define BN 64
#define JSPLIT 8
#define JRANGE (N_ROWS / JSPLIT)     // 1024
#define NT (JRANGE / BN)             // 16 j-steps per block

typedef __attribute__((ext_vector_type(4))) float f32x4;

// total scale: exp(dot*2) == exp2(dot * 2*log2(e)); sqrt folded onto A and B
#define CAST_SCALE 1.6986388f        // sqrt(2 * log2(e))

__device__ __forceinline__ float fast_exp2(float x) {
#if __has_builtin(__builtin_amdgcn_exp2f)
    return __builtin_amdgcn_exp2f(x);
#else
    return exp2f(x);
#endif
}

// ------- kernel 1: L2-normalize rows, scale, cast to fp8 e4m3 (+ zero accum) -
__global__ void norm_cast_kernel(const float* __restrict__ out0,
                                 const float* __restrict__ out1,
                                 unsigned char* __restrict__ a_f8,
                                 unsigned char* __restrict__ b_f8,
                                 float* __restrict__ zero_me) {   // pos+all, 2*N floats
    int gtid = blockIdx.x * blockDim.x + threadIdx.x;
    if (gtid < 2 * N_ROWS) zero_me[gtid] = 0.0f;

    int wave = gtid >> 6;
    int lane = threadIdx.x & 63;
    const float* src    = (wave < N_ROWS) ? out0 : out1;
    unsigned char* dst  = (wave < N_ROWS) ? a_f8 : b_f8;
    int row = (wave < N_ROWS) ? wave : wave - N_ROWS;

    float4 v = *reinterpret_cast<const float4*>(src + (size_t)row * D_DIM + lane * 4);
    float ss = v.x * v.x + v.y * v.y + v.z * v.z + v.w * v.w;
    #pragma unroll
    for (int off = 32; off; off >>= 1) ss += __shfl_xor(ss, off);
    float inv = CAST_SCALE / fmaxf(sqrtf(ss), 1e-12f);

    int packed = __builtin_amdgcn_cvt_pk_fp8_f32(v.x * inv, v.y * inv, 0, 0);
    packed     = __builtin_amdgcn_cvt_pk_fp8_f32(v.z * inv, v.w * inv, packed, 1);
    *reinterpret_cast<unsigned int*>(dst + (size_t)row * D_DIM + lane * 4) =
        (unsigned int)packed;
}

// ------- kernel 2: fp8 flash-style fused GEMM + exp2 + masked row-sums ------
// r7 structure (proven): 512 blocks = 64 row-tiles x 8 j-splits, 4 waves in
// 2x2, wave-tile 64x32. fp8 halves the LDS-read pipe and the A-pin (64 VGPR).
// K-permutation trick: each 16B slot holds (ks=2j | ks=2j+1) fragments for one
// kgrp; A loaded with the SAME byte mapping, so b128 LDS reads stay
// conflict-free (r7's verified swizzle pattern: phys_slot = log_slot ^ lane16).
__global__ __launch_bounds__(256, 2)
void fused_flash_kernel(const unsigned char* __restrict__ A,
                        const unsigned char* __restrict__ B,
                        const int* __restrict__ labels,
                        float* __restrict__ pos_sum,
                        float* __restrict__ all_sum) {
    __shared__ unsigned char Bs[2][BN * D_DIM];   // 2 x 16 KB

    const int tid    = threadIdx.x;
    const int lane   = tid & 63;
    const int wid    = tid >> 6;        // 0..3
    const int wr     = wid >> 1;        // 0..1  (64-row band)
    const int wc     = wid & 1;         // 0..1  (32-col half)
    const int lane16 = lane & 15;
    const int kgrp   = lane >> 4;       // 0..3

    const int jsplit = blockIdx.x & 7;
    const int rowt   = blockIdx.x >> 3;
    const int i0     = rowt * BM;
    const int jbase  = jsplit * JRANGE;

    // ---- A fragments -> registers (once), PINNED (64 VGPR fp8) ----
    // b128 at row bytes [j*64 + kgrp*16, +16): low 8B -> ks=2j, high -> ks=2j+1
    long af[4][8];
    #pragma unroll
    for (int m = 0; m < 4; ++m) {
        const unsigned char* ap =
            A + (size_t)(i0 + wr * 64 + m * 16 + lane16) * D_DIM + kgrp * 16;
        #pragma unroll
        for (int j = 0; j < 4; ++j) {
            long2 v = *reinterpret_cast<const long2*>(ap + j * 64);
            af[m][2 * j]     = v.x;
            af[m][2 * j + 1] = v.y;
        }
    }
    #pragma unroll
    for (int m = 0; m < 4; ++m)
        #pragma unroll
        for (int ks = 0; ks < 8; ++ks)
            asm volatile("" : "+v"(af[m][ks]));

    // row labels (0..99 fit in a byte), packed 4-per-int, pinned
    int labp[4];
    #pragma unroll
    for (int m = 0; m < 4; ++m) {
        int4 v = *reinterpret_cast<const int4*>(labels + i0 + wr * 64 + m * 16 + kgrp * 4);
        labp[m] = v.x | (v.y << 8) | (v.z << 16) | (v.w << 24);
        asm volatile("" : "+v"(labp[m]));
    }

    // ---- B staging: 16 chunks of 1KB (4 rows x 256B), 4 per wave ----
    // LDS[row][phys] = global[row][phys ^ (row&15)]  (16B slots, 16 per row)
    auto stage = [&](int buf, int t) {
        const int jrow0 = jbase + t * BN;
        #pragma unroll
        for (int cc = 0; cc < 4; ++cc) {
            int c  = wid * 4 + cc;                  // chunk 0..15 (wave-uniform)
            int gr = jrow0 + c * 4 + kgrp;          // global B row
            const unsigned char* src =
                B + (size_t)gr * D_DIM + ((lane16 ^ (gr & 15)) << 4);
            __builtin_amdgcn_global_load_lds(
                (const __attribute__((address_space(1))) void*)src,
                (__attribute__((address_space(3))) void*)(&Bs[buf][0] + c * 1024),
                16, 0, 0);
        }
    };

    float allp[4][4] = {};
    float posp[4][4] = {};

    stage(0, 0);
    __syncthreads();

    for (int t = 0; t < NT; ++t) {
        const int cur = t & 1;
        if (t + 1 < NT) stage(cur ^ 1, t + 1);

        // column labels early (hide under MFMA)
        const int jc    = jbase + t * BN + wc * 32 + lane16;
        const int labc0 = labels[jc];
        const int labc1 = labels[jc + 16];

        // ---- hoist all 8 b128 B-loads, then 64 MFMAs ----
        long bl[2][4], bh[2][4];
        #pragma unroll
        for (int n = 0; n < 2; ++n) {
            const int tr = wc * 32 + n * 16 + lane16;     // B row (output col)
            #pragma unroll
            for (int j = 0; j < 4; ++j) {
                int phys = (j * 4 + kgrp) ^ lane16;       // swizzled 16B slot
                long2 v = *reinterpret_cast<const long2*>(
                    &Bs[cur][0] + tr * 256 + (phys << 4));
                bl[n][j] = v.x;                           // ks = 2j
                bh[n][j] = v.y;                           // ks = 2j+1
            }
        }

        f32x4 acc[4][2] = {};
        __builtin_amdgcn_s_setprio(1);
        #pragma unroll
        for (int j = 0; j < 4; ++j) {
            #pragma unroll
            for (int m = 0; m < 4; ++m)
                #pragma unroll
                for (int n = 0; n < 2; ++n)
                    acc[m][n] = __builtin_amdgcn_mfma_f32_16x16x32_fp8_fp8(
                        af[m][2 * j], bl[n][j], acc[m][n], 0, 0, 0);
            #pragma unroll
            for (int m = 0; m < 4; ++m)
                #pragma unroll
                for (int n = 0; n < 2; ++n)
                    acc[m][n] = __builtin_amdgcn_mfma_f32_16x16x32_fp8_fp8(
                        af[m][2 * j + 1], bh[n][j], acc[m][n], 0, 0, 0);
        }
        __builtin_amdgcn_s_setprio(0);

        __syncthreads();   // all reads of Bs[cur] done; stage(t+1) drained

        // ---- epilogue: exp2 + mask, accumulate row sums in registers ----
        #pragma unroll
        for (int m = 0; m < 4; ++m) {
            #pragma unroll
            for (int r = 0; r < 4; ++r) {
                float e0 = fast_exp2(acc[m][0][r]);   // == exp(logit/T)
                float e1 = fast_exp2(acc[m][1][r]);
                allp[m][r] += e0 + e1;
                int lr = (labp[m] >> (r * 8)) & 0xFF;
                posp[m][r] += (lr == labc0 ? e0 : 0.0f) + (lr == labc1 ? e1 : 0.0f);
            }
        }
    }

    // ---- final: reduce across the 16 col-lanes, one atomic per row ----
    #pragma unroll
    for (int m = 0; m < 4; ++m) {
        #pragma unroll
        for (int r = 0; r < 4; ++r) {
            float a = allp[m][r], p = posp[m][r];
            #pragma unroll
            for (int off = 1; off < 16; off <<= 1) {
                a += __shfl_xor(a, off);
                p += __shfl_xor(p, off);
            }
            if (lane16 == 0) {
                int grow = i0 + wr * 64 + m * 16 + kgrp * 4 + r;
                atomicAdd(&all_sum[grow], a);
                atomicAdd(&pos_sum[grow], p);
            }
        }
    }
}

// ---------------- kernel 3: final loss reduction ----------------------------
__global__ void loss_kernel(const float* __restrict__ pos_sum,
                            const float* __restrict__ all_sum,
                            float* __restrict__ out) {
    float acc = 0.0f;
    for (int i = threadIdx.x; i < N_ROWS; i += 1024)
        acc += logf(pos_sum[i] / all_sum[i]);
    #pragma unroll
    for (int off = 32; off; off >>= 1) acc += __shfl_xor(acc, off);
    __shared__ float red[16];
    int wv = threadIdx.x >> 6, lane = threadIdx.x & 63;
    if (lane == 0) red[wv] = acc;
    __syncthreads();
    if (threadIdx.x < 64) {
        float s = (threadIdx.x < 16) ? red[threadIdx.x] : 0.0f;
        #pragma unroll
        for (int off = 8; off; off >>= 1) s += __shfl_xor(s, off);
        if (threadIdx.x == 0) out[0] = -s / (float)N_ROWS;
    }
}

// ---------------- launch -----------------------------------------------------
extern "C" void kernel_launch(void* const* d_in, const int* in_sizes, int n_in,
                              void* d_out, int out_size, void* d_ws, size_t ws_size,
                              hipStream_t stream) {
    const float* out0   = (const float*)d_in[0];
    const float* out1   = (const float*)d_in[1];
    const int*   labels = (const int*)d_in[2];
    float*       out    = (float*)d_out;

    unsigned char* a_f8 = (unsigned char*)d_ws;
    unsigned char* b_f8 = a_f8 + (size_t)N_ROWS * D_DIM;
    float* pos  = (float*)(b_f8 + (size_t)N_ROWS * D_DIM);
    float* alls = pos + N_ROWS;

    norm_cast_kernel<<<2 * N_ROWS / 4, 256, 0, stream>>>(out0, out1, a_f8, b_f8, pos);

    fused_flash_kernel<<<JSPLIT * (N_ROWS / BM), 256, 0, stream>>>(a_f8, b_f8, labels, pos, alls);

    loss_kernel<<<1, 1024, 0, stream>>>(pos, alls, out);
}